// Round 12
// baseline (132.334 us; speedup 1.0000x reference)
//
#include <hip/hip_runtime.h>
#include <hip/hip_bf16.h>
#include <math.h>

#define Nn 50000
#define Ee 800000
#define Cc 16
#define Mm 32
#define Gg 8
#define CAPk 44           // per-node edge-slot capacity (max deg ~35; P(>44)~1e-10/node)

#define P1B 250           // pass-1 blocks (800 int4 quads = 3200 edges each)
#define NBK 512           // src-range buckets
#define BSZ 98            // nodes per bucket (512*98 = 50176 >= 50000)
#define SEGE 24           // edge capacity per (block,bucket) cell (mean 6.3; same as prior rounds)
#define SEGW 25           // strip stride: [count][e0..e23]
#define L0B 517           // layer0 blocks (grid 250+517+1 = 768 = 3/CU exact)

// ---------------------------------------------------------------------------
// helpers
// ---------------------------------------------------------------------------
__device__ __forceinline__ float ldin(const void* p, int idx, int isbf) {
    if (isbf) return __bfloat162float(((const __hip_bfloat16*)p)[idx]);
    return ((const float*)p)[idx];
}
__device__ __forceinline__ void stout(void* p, size_t idx, float v, int isbf) {
    if (isbf) ((__hip_bfloat16*)p)[idx] = __float2bfloat16(v);
    else ((float*)p)[idx] = v;
}
__device__ __forceinline__ unsigned short f2bf(float f) {    // RNE f32 -> bf16 bits
    unsigned u = __float_as_uint(f);
    return (unsigned short)((u + 0x7FFFu + ((u >> 16) & 1u)) >> 16);
}
__device__ __forceinline__ float bflo(unsigned v) { return __uint_as_float(v << 16); }
__device__ __forceinline__ float bfhi(unsigned v) { return __uint_as_float(v & 0xffff0000u); }

__device__ __forceinline__ int detect_bf16(const void* B0, int tid, int* sflag) {
    if (tid < 64) {
        unsigned wv = ((const unsigned*)B0)[tid];
        unsigned ex = (wv >> 7) & 0xFFu;
        unsigned long long m = __ballot(ex >= 120u && ex <= 130u);
        if (tid == 0) *sflag = (__popcll(m) >= 48) ? 1 : 0;
    }
    __syncthreads();
    return *sflag;
}

// in-place softmax of one LDS column: entries base + k*stride, k in [0,cnt)
__device__ __forceinline__ void sm_col(float* a, int base, int stride, int cnt) {
    float mx = -1e30f;
    for (int k = 0; k < cnt; ++k) mx = fmaxf(mx, a[base + k * stride]);
    float s = 0.f;
    for (int k = 0; k < cnt; ++k) {
        float e = __expf(a[base + k * stride] - mx);
        a[base + k * stride] = e;
        s += e;
    }
    float inv = 1.0f / s;
    for (int k = 0; k < cnt; ++k) a[base + k * stride] *= inv;
}

// ---------------------------------------------------------------------------
// Kernel 1: blocks [0,P1B)          = pass-1 edge bucket-scatter (LDS atomics)
//           blocks [P1B,P1B+L0B)    = layer0
//           block  P1B+L0B          = layer-1 table producer + zero-row
// R12 change: segcnt array ELIMINATED — counts embedded as word 0 of each
// 25-word strip cell. Kills 128K scattered single-word segcnt stores (~16MB
// partial-line fabric writes, the last unexplained K1 cost suspect). Flush
// writes each cell's full 100B unconditionally (dense, poison-safe).
// ---------------------------------------------------------------------------
__global__ void bucket_layer0(const int* __restrict__ ei,
                              const int* __restrict__ x,
                              const void* __restrict__ B0,
                              const void* __restrict__ Pi,
                              const void* __restrict__ B1,
                              const void* __restrict__ Q,
                              unsigned* __restrict__ segbuf,   // [NBK][P1B][SEGW]
                              unsigned short* __restrict__ post0,
                              float* __restrict__ smB1ws,      // [i][m][g] fp32
                              float* __restrict__ smQgws,      // [g][i][l] fp32
                              int* __restrict__ flag_ws,
                              void* __restrict__ out) {
    int b = blockIdx.x, tid = threadIdx.x;
    __shared__ unsigned shb[NBK + NBK * SEGE];     // 51.2 KB unioned buffer
    __shared__ int sflag;

    if (b < P1B) {   // ---- pass 1: bucket scatter ----
        int* scnt = (int*)shb;            // 512 counters
        unsigned* sstage = shb + NBK;     // 512*24 staged packed edges
        for (int i = tid; i < NBK; i += 256) scnt[i] = 0;
        __syncthreads();
        const int4* ei4 = (const int4*)ei;
        const int qbase = b * 800;                 // 800 quads = 3200 edges per block
        for (int q = tid; q < 800; q += 256) {
            int4 sv = ei4[qbase + q];
            int4 dv = ei4[200000 + qbase + q];     // Ee/4 = 200000
#pragma unroll
            for (int k = 0; k < 4; ++k) {
                int s = (k == 0) ? sv.x : (k == 1) ? sv.y : (k == 2) ? sv.z : sv.w;
                int d = (k == 0) ? dv.x : (k == 1) ? dv.y : (k == 2) ? dv.z : dv.w;
                int bk = s / BSZ;                  // magic-mul division
                int pos = atomicAdd(&scnt[bk], 1); // LDS atomic (on-CU, cheap)
                if (pos < SEGE)
                    sstage[bk * SEGE + pos] = ((unsigned)(s - bk * BSZ) << 16) | (unsigned)d;
            }
        }
        __syncthreads();
        // flush: full 25-word cell per bucket, word 0 = count, dense stores
        for (int idx = tid; idx < NBK * SEGW; idx += 256) {
            int bk = idx / SEGW;                   // magic-mul
            int j  = idx - bk * SEGW;
            int c  = scnt[bk]; c = c < SEGE ? c : SEGE;
            unsigned v = (j == 0) ? (unsigned)c : sstage[bk * SEGE + (j - 1)];
            segbuf[((size_t)bk * P1B + b) * SEGW + j] = v;
        }
        return;
    }

    float* sh = (float*)shb;                // alias: 4224 floats used

    if (b == P1B + L0B) {   // ---- layer-1 table producer + zero-row ----
        if (tid < 16) {
            uint4 z; z.x = 0u; z.y = 0u; z.z = 0u; z.w = 0u;
            ((uint4*)(post0 + (size_t)Nn * 128))[tid] = z;
        }
        const int isbf = detect_bf16(B0, tid, &sflag);
        if (tid == 0) flag_ws[0] = isbf;
        // Phase A: B1 softmax -> smB1ws
        for (int i = tid; i < Cc * Mm * Gg; i += 256) sh[i] = ldin(B1, i, isbf);
        __syncthreads();
        if (tid < 128) sm_col(sh, (tid >> 3) * (Mm * Gg) + (tid & 7), Gg, Mm);
        __syncthreads();
        for (int i = tid; i < Cc * Mm * Gg; i += 256) smB1ws[i] = sh[i];
        __syncthreads();
        // Phase B: Q softmax -> smQgws ([g][i][l] relayout)
        for (int i = tid; i < Cc * Cc * Gg; i += 256) sh[i] = ldin(Q, i, isbf);
        __syncthreads();
        if (tid < 128) sm_col(sh, (tid >> 3) * Gg + (tid & 7), Cc * Gg, Cc);
        __syncthreads();
        for (int t = tid; t < Cc * Cc * Gg; t += 256) {
            int i = t >> 7, rem = t & 127, l = rem >> 3, g = rem & 7;
            smQgws[g * (Cc * Cc) + i * Cc + l] = sh[t];
        }
        return;
    }

    // ---- layer0 ----
    float* sB0sm = sh;                      // 4096, [c][m][g]
    float* sPism = sh + 4096;               // 128,  [c][g]
    const int isbf = detect_bf16(B0, tid, &sflag);

    for (int i = tid; i < Cc * Mm * Gg; i += 256) sB0sm[i] = ldin(B0, i, isbf);
    if (tid < Cc * Gg) sPism[tid] = ldin(Pi, tid, isbf);
    __syncthreads();
    if (tid < 128) {                        // B0 col (c,g): softmax over m, stride 8
        sm_col(sB0sm, (tid >> 3) * (Mm * Gg) + (tid & 7), Gg, Mm);
    } else if (tid < 128 + Gg) {            // Pi col g: softmax over c, stride 8
        sm_col(sPism, tid - 128, Gg, Cc);
    }
    __syncthreads();

    for (int idx = (b - P1B) * 256 + tid; idx < Nn * Gg; idx += L0B * 256) {
        int n = idx >> 3, g = idx & 7;
        int xv = x[n];
        float u[Cc];
        float norm = 0.f;
#pragma unroll
        for (int c = 0; c < Cc; ++c) {
            float v = sPism[c * Gg + g] * sB0sm[c * (Mm * Gg) + xv * Gg + g];
            u[c] = v; norm += v;
        }
        float inv = 1.0f / norm;
        unsigned short h[Cc];
#pragma unroll
        for (int c = 0; c < Cc; ++c) h[c] = f2bf(u[c] * inv);
        uint4 w0, w1;
        w0.x = h[0] | (h[1] << 16);   w0.y = h[2] | (h[3] << 16);
        w0.z = h[4] | (h[5] << 16);   w0.w = h[6] | (h[7] << 16);
        w1.x = h[8] | (h[9] << 16);   w1.y = h[10] | (h[11] << 16);
        w1.z = h[12] | (h[13] << 16); w1.w = h[14] | (h[15] << 16);
        uint4* dst = (uint4*)(post0 + (size_t)n * 128 + g * 16);
        dst[0] = w0; dst[1] = w1;
        stout(out, (size_t)n * (2 * Gg) + g, logf(norm), isbf);
    }
}

// ---------------------------------------------------------------------------
// Kernel 2 (R12): place+aggr with CAPk=44 -> LDS 35.2KB -> 4 blocks/CU =
// 32 waves/CU (was 3 blocks / 24 waves). Counts read from strip word 0.
// Aggr inner loop byte-identical to R9/R11. Second (clean) occupancy test.
// ---------------------------------------------------------------------------
#define GL2(vv, eb, nn, dde) { int ej_ = (eb) + sub16; \
    int dn_ = (ej_ < (dde)) ? (int)list[(nn) * CAPk + ej_] : Nn; \
    unsigned off_ = ((unsigned)dn_ << 8) + mbyte; \
    vv = *(const uint4*)((const char*)post0 + off_); }
#define GACC(vv) { \
    acc[0] += bflo(vv.x); acc[1] += bfhi(vv.x); acc[2] += bflo(vv.y); acc[3] += bfhi(vv.y); \
    acc[4] += bflo(vv.z); acc[5] += bfhi(vv.z); acc[6] += bflo(vv.w); acc[7] += bfhi(vv.w); }

__global__ __launch_bounds__(512) void place_aggr(
        const unsigned* __restrict__ segbuf,   // [NBK][P1B][SEGW]
        const unsigned short* __restrict__ post0,
        const int* __restrict__ x,
        const float* __restrict__ smB1ws,
        const float* __restrict__ smQgws,
        const int* __restrict__ flag_ws,
        void* __restrict__ out) {
    __shared__ unsigned list[BSZ * CAPk];   // 17.2 KB per-node dst lists
    __shared__ int cnt[BSZ];
    __shared__ int scl[P1B];                // 250 segment counts (from strip word 0)
    __shared__ float sQ[4341];              // 17.4 KB swizzled Q table
    int b = blockIdx.x, tid = threadIdx.x;
    const int isbf = flag_ws[0];
    const unsigned* strip = segbuf + (size_t)b * (P1B * SEGW);

    for (int t = tid; t < Cc * Cc * Gg; t += 512) {
        int g = t >> 8, i = (t >> 4) & 15, j = t & 15;
        sQ[g * 545 + i * 34 + j] = smQgws[t];
    }
    for (int i = tid; i < BSZ; i += 512) cnt[i] = 0;
    if (tid < P1B) scl[tid] = (int)strip[tid * SEGW];   // count words
    __syncthreads();

    {   // ---- place: coalesced 25KB strip scan ----
        for (int w = tid; w < P1B * SEGW; w += 512) {
            unsigned pk = strip[w];                    // coalesced load
            int seg = w / SEGW;                        // magic-mul
            int j   = w - seg * SEGW;
            if (j >= 1 && j <= scl[seg]) {
                int sl = (int)(pk >> 16);
                int pos = atomicAdd(&cnt[sl], 1);      // LDS atomic
                if (pos < CAPk) list[sl * CAPk + pos] = pk & 0xffffu;
            }
        }
    }
    __syncthreads();

    // ---- aggregation + layer1 (byte-identical to R9/R11) ----
    const int lane = tid & 63, wib = tid >> 6;     // 8 waves
    const int sub16 = lane >> 4;
    const unsigned mbyte = (unsigned)((lane & 15) * 16);
    const int ii = lane >> 3, gW = lane & 7;
    const int i0 = 2 * ii, i1 = i0 + 1;
    const float* qp = sQ + gW * 545 + i0 * 34;
    const int nbase = b * BSZ;
    int limt = Nn - nbase; if (limt > BSZ) limt = BSZ;   // nodes in this block
    const int lim = limt;

    int n = wib;
    // prologue: meta + first-16 gather for node n
    int dv0 = 0, dd0 = 0; float b0c = 0.f, b1c = 0.f;
    uint4 bA0, bA1, bA2, bA3;
    bA0.x = bA0.y = bA0.z = bA0.w = 0u; bA1 = bA0; bA2 = bA0; bA3 = bA0;
    if (n < lim) {
        dv0 = __builtin_amdgcn_readfirstlane(cnt[n]);
        dd0 = dv0 < CAPk ? dv0 : CAPk;
        int xv = x[nbase + n];
        b0c = smB1ws[i0 * (Mm * Gg) + xv * Gg + gW];
        b1c = smB1ws[i1 * (Mm * Gg) + xv * Gg + gW];
        GL2(bA0, 0, n, dd0); GL2(bA1, 4, n, dd0); GL2(bA2, 8, n, dd0); GL2(bA3, 12, n, dd0);
    }

    while (n < lim) {
        int n1 = n + 8;
        // prefetch node n1 (meta + first-16 gather)
        int dv1 = 0, dd1 = 0; float b0n = 0.f, b1n = 0.f;
        uint4 bB0, bB1, bB2, bB3;
        bB0.x = bB0.y = bB0.z = bB0.w = 0u; bB1 = bB0; bB2 = bB0; bB3 = bB0;
        if (n1 < lim) {
            dv1 = __builtin_amdgcn_readfirstlane(cnt[n1]);
            dd1 = dv1 < CAPk ? dv1 : CAPk;
            int xv = x[nbase + n1];
            b0n = smB1ws[i0 * (Mm * Gg) + xv * Gg + gW];
            b1n = smB1ws[i1 * (Mm * Gg) + xv * Gg + gW];
            GL2(bB0, 0, n1, dd1); GL2(bB1, 4, n1, dd1); GL2(bB2, 8, n1, dd1); GL2(bB3, 12, n1, dd1);
        }

        // consume node n
        float acc[8];
#pragma unroll
        for (int j = 0; j < 8; ++j) acc[j] = 0.f;
        GACC(bA0); GACC(bA1); GACC(bA2); GACC(bA3);
        for (int e = 16; e < dd0; e += 16) {       // deg>16 tail
            uint4 t0, t1, t2, t3;
            GL2(t0, e, n, dd0); GL2(t1, e + 4, n, dd0);
            GL2(t2, e + 8, n, dd0); GL2(t3, e + 12, n, dd0);
            GACC(t0); GACC(t1); GACC(t2); GACC(t3);
        }

#pragma unroll
        for (int j = 0; j < 8; ++j) {
            acc[j] += __shfl_xor(acc[j], 16, 64);
            acc[j] += __shfl_xor(acc[j], 32, 64);
        }
        float qa0 = 0.f, qa1 = 0.f;
#pragma unroll
        for (int j = 0; j < 8; ++j) {
            float t0 = __shfl(acc[j], 2 * gW, 64);
            float t1 = __shfl(acc[j], 2 * gW + 1, 64);
            qa0 += qp[j] * t0 + qp[8 + j] * t1;
            qa1 += qp[34 + j] * t0 + qp[42 + j] * t1;
        }
        float invd = 1.0f / fmaxf((float)dv0, 1.0f);
        qa0 *= invd; qa1 *= invd;
        float v0 = b0c * qa0, v1 = b1c * qa1;
        float nrm = v0 + v1;
        nrm += __shfl_xor(nrm, 8, 64);
        nrm += __shfl_xor(nrm, 16, 64);
        nrm += __shfl_xor(nrm, 32, 64);
        float invn = 1.0f / nrm;
        int ng = nbase + n;
        size_t pbase = (size_t)Nn * 2 * Gg + (size_t)ng * (Cc * Gg);
        stout(out, pbase + i0 * Gg + gW, v0 * invn, isbf);
        stout(out, pbase + i1 * Gg + gW, v1 * invn, isbf);
        if (ii == 0) stout(out, (size_t)ng * (2 * Gg) + Gg + gW, logf(nrm), isbf);

        // rotate pipeline
        n = n1;
        dv0 = dv1; dd0 = dd1; b0c = b0n; b1c = b1n;
        bA0 = bB0; bA1 = bB1; bA2 = bB2; bA3 = bB3;
    }
}

// ---------------------------------------------------------------------------
extern "C" void kernel_launch(void* const* d_in, const int* in_sizes, int n_in,
                              void* d_out, int out_size, void* d_ws, size_t ws_size,
                              hipStream_t stream) {
    const int* x  = (const int*)d_in[0];
    const int* ei = (const int*)d_in[1];
    const void* B0 = d_in[2];
    const void* Pi = d_in[3];
    const void* B1 = d_in[4];
    const void* Q  = d_in[5];

    // ws: flag(128) | smB1(4096) | smQg(2048) | post0 ((Nn+1)*128 bf16)
    //   | segbuf (NBK*P1B*SEGW u32 = 12.8MB)
    float* ws = (float*)d_ws;
    int*   flag   = (int*)ws;                     // [0]=isbf
    float* smB1ws = ws + 128;                     // 4096 [i][m][g]
    float* smQgws = smB1ws + 4096;                // 2048 [g][i][l]
    unsigned short* post0 = (unsigned short*)(smQgws + 2048);  // (Nn+1)*128 bf16
    unsigned* segbuf = (unsigned*)(post0 + (size_t)(Nn + 1) * 128);  // [NBK][P1B][SEGW]

    bucket_layer0<<<P1B + L0B + 1, 256, 0, stream>>>(
        ei, x, B0, Pi, B1, Q, segbuf, post0, smB1ws, smQgws, flag, d_out);

    place_aggr<<<NBK, 512, 0, stream>>>(
        segbuf, post0, x, smB1ws, smQgws, flag, d_out);
}

// Round 13
// 131.152 us; speedup vs baseline: 1.0090x; 1.0090x over previous
//
#include <hip/hip_runtime.h>
#include <hip/hip_bf16.h>
#include <math.h>

#define Nn 50000
#define Ee 800000
#define Cc 16
#define Mm 32
#define Gg 8
#define CAPk 44           // per-node edge-slot capacity (max deg ~35)

#define P1B 250           // pass-1 blocks (800 int4 quads = 3200 edges each)
#define NBK 512           // src-range buckets
#define BSZ 98            // nodes per bucket (512*98 = 50176 >= 50000)
#define SEGE 24           // edge capacity per (block,bucket) cell (mean 6.25)
#define SEGW 25           // strip stride: [count][e0..e23]
#define RROW 136          // R row stride in bf16 (128 data + 8 pad; 272B, 16B-aligned rows)

// ---------------------------------------------------------------------------
// helpers
// ---------------------------------------------------------------------------
__device__ __forceinline__ float ldin(const void* p, int idx, int isbf) {
    if (isbf) return __bfloat162float(((const __hip_bfloat16*)p)[idx]);
    return ((const float*)p)[idx];
}
__device__ __forceinline__ void stout(void* p, size_t idx, float v, int isbf) {
    if (isbf) ((__hip_bfloat16*)p)[idx] = __float2bfloat16(v);
    else ((float*)p)[idx] = v;
}
__device__ __forceinline__ unsigned short f2bf(float f) {    // RNE f32 -> bf16 bits
    unsigned u = __float_as_uint(f);
    return (unsigned short)((u + 0x7FFFu + ((u >> 16) & 1u)) >> 16);
}
__device__ __forceinline__ float bflo(unsigned v) { return __uint_as_float(v << 16); }
__device__ __forceinline__ float bfhi(unsigned v) { return __uint_as_float(v & 0xffff0000u); }

__device__ __forceinline__ int detect_bf16(const void* B0, int tid, int* sflag) {
    if (tid < 64) {
        unsigned wv = ((const unsigned*)B0)[tid];
        unsigned ex = (wv >> 7) & 0xFFu;
        unsigned long long m = __ballot(ex >= 120u && ex <= 130u);
        if (tid == 0) *sflag = (__popcll(m) >= 48) ? 1 : 0;
    }
    __syncthreads();
    return *sflag;
}

// in-place softmax of one LDS column: entries base + k*stride, k in [0,cnt)
__device__ __forceinline__ void sm_col(float* a, int base, int stride, int cnt) {
    float mx = -1e30f;
    for (int k = 0; k < cnt; ++k) mx = fmaxf(mx, a[base + k * stride]);
    float s = 0.f;
    for (int k = 0; k < cnt; ++k) {
        float e = __expf(a[base + k * stride] - mx);
        a[base + k * stride] = e;
        s += e;
    }
    float inv = 1.0f / s;
    for (int k = 0; k < cnt; ++k) a[base + k * stride] *= inv;
}

// ---------------------------------------------------------------------------
// Kernel 1 (R13): blocks [0,P1B) = pass-1 scatter; block P1B = table producer.
// KEY INSIGHT: post0[n] depends ONLY on x[n] (32 symbols) -> the 12.8MB
// post0 table is 32 distinct rows (8KB). Pass-1 resolves x[dst] at scatter
// time and packs (s_local<<5)|xv into 12-bit words; the layer0 phase (517
// blocks, 12.8MB of post0 writes) is DELETED. Table block produces the
// pre-normalized bf16 row table R (33 rows; row 32 = zeros for OOB) and
// lntab = log(norm) per (symbol,g) (ll0 output = lntab[x[n]][g], moved to K2).
// ---------------------------------------------------------------------------
__global__ void bucket_tables(const int* __restrict__ ei,
                              const int* __restrict__ x,
                              const void* __restrict__ B0,
                              const void* __restrict__ Pi,
                              const void* __restrict__ B1,
                              const void* __restrict__ Q,
                              unsigned* __restrict__ segbuf,     // [NBK][P1B][SEGW]
                              unsigned short* __restrict__ Rws,  // [33][RROW] bf16
                              float* __restrict__ lntabws,       // [32][8]
                              float* __restrict__ smB1ws,        // [i][m][g] fp32
                              float* __restrict__ smQgws,        // [g][i][l] fp32
                              int* __restrict__ flag_ws,
                              void* __restrict__ out) {
    int b = blockIdx.x, tid = threadIdx.x;
    __shared__ unsigned shb[NBK + NBK * SEGE];     // 51.2 KB unioned buffer
    __shared__ int sflag;

    if (b < P1B) {   // ---- pass 1: bucket scatter with symbol resolution ----
        int* scnt = (int*)shb;            // 512 counters
        unsigned* sstage = shb + NBK;     // 512*24 staged packed words
        for (int i = tid; i < NBK; i += 256) scnt[i] = 0;
        __syncthreads();
        const int4* ei4 = (const int4*)ei;
        const int qbase = b * 800;                 // 800 quads = 3200 edges
        for (int q = tid; q < 800; q += 256) {
            int4 sv = ei4[qbase + q];
            int4 dv = ei4[200000 + qbase + q];     // Ee/4 = 200000
            int ds_[4] = { dv.x, dv.y, dv.z, dv.w };
            int xs_[4];
#pragma unroll
            for (int k = 0; k < 4; ++k) xs_[k] = x[ds_[k]];   // 4 batched L2 loads
#pragma unroll
            for (int k = 0; k < 4; ++k) {
                int s = (k == 0) ? sv.x : (k == 1) ? sv.y : (k == 2) ? sv.z : sv.w;
                int bk = s / BSZ;                  // magic-mul division
                int pos = atomicAdd(&scnt[bk], 1); // LDS atomic
                if (pos < SEGE)
                    sstage[bk * SEGE + pos] =
                        ((unsigned)(s - bk * BSZ) << 5) | (unsigned)xs_[k];
            }
        }
        __syncthreads();
        // dense flush: full 25-word cell per bucket, word 0 = count
        for (int idx = tid; idx < NBK * SEGW; idx += 256) {
            int bk = idx / SEGW;
            int j  = idx - bk * SEGW;
            int c  = scnt[bk]; c = c < SEGE ? c : SEGE;
            unsigned v = (j == 0) ? (unsigned)c : sstage[bk * SEGE + (j - 1)];
            segbuf[((size_t)bk * P1B + b) * SEGW + j] = v;
        }
        return;
    }

    // ---- table producer block (b == P1B), three sequential phases ----
    float* sh = (float*)shb;                // 4480 floats used of 12800
    const int isbf = detect_bf16(B0, tid, &sflag);
    if (tid == 0) flag_ws[0] = isbf;
    // Phase 1: B1 softmax -> smB1ws
    for (int i = tid; i < Cc * Mm * Gg; i += 256) sh[i] = ldin(B1, i, isbf);
    __syncthreads();
    if (tid < 128) sm_col(sh, (tid >> 3) * (Mm * Gg) + (tid & 7), Gg, Mm);
    __syncthreads();
    for (int i = tid; i < Cc * Mm * Gg; i += 256) smB1ws[i] = sh[i];
    __syncthreads();
    // Phase 2: Q softmax -> smQgws ([g][i][l] relayout)
    for (int i = tid; i < Cc * Cc * Gg; i += 256) sh[i] = ldin(Q, i, isbf);
    __syncthreads();
    if (tid < 128) sm_col(sh, (tid >> 3) * Gg + (tid & 7), Cc * Gg, Cc);
    __syncthreads();
    for (int t = tid; t < Cc * Cc * Gg; t += 256) {
        int i = t >> 7, rem = t & 127, l = rem >> 3, g = rem & 7;
        smQgws[g * (Cc * Cc) + i * Cc + l] = sh[t];
    }
    __syncthreads();
    // Phase 3: B0 + Pi softmax -> R rows (bf16) + lntab
    float* sB0 = sh;                        // 4096, [c][m][g]
    float* sPi = sh + 4096;                 // 128,  [c][g]
    float* sInv = sh + 4224;                // 256,  [m][g] 1/norm
    for (int i = tid; i < Cc * Mm * Gg; i += 256) sB0[i] = ldin(B0, i, isbf);
    if (tid < Cc * Gg) sPi[tid] = ldin(Pi, tid, isbf);
    __syncthreads();
    if (tid < 128) {                        // B0 col (c,g): softmax over m
        sm_col(sB0, (tid >> 3) * (Mm * Gg) + (tid & 7), Gg, Mm);
    } else if (tid < 128 + Gg) {            // Pi col g: softmax over c
        sm_col(sPi, tid - 128, Gg, Cc);
    }
    __syncthreads();
    if (tid < Mm * Gg) {                    // norms per (symbol m, g)
        int mm = tid >> 3, g = tid & 7;
        float s = 0.f;
#pragma unroll
        for (int c = 0; c < Cc; ++c) s += sPi[c * Gg + g] * sB0[c * (Mm * Gg) + mm * Gg + g];
        lntabws[tid] = logf(s);
        sInv[tid] = 1.0f / s;
    }
    __syncthreads();
    for (int idx = tid; idx < 33 * RROW; idx += 256) {   // bf16 R rows (+zero row 32)
        int row = idx / RROW, rem = idx - row * RROW;
        unsigned short v = 0;
        if (row < 32 && rem < 128) {
            int g = rem >> 4, c = rem & 15;              // rem = g*16+c
            float pv = sPi[c * Gg + g] * sB0[c * (Mm * Gg) + row * Gg + g] * sInv[row * Gg + g];
            v = f2bf(pv);
        }
        Rws[idx] = v;
    }
}

// ---------------------------------------------------------------------------
// Kernel 2 (R13): place + aggregation + BOTH layer outputs, gather ALL-LDS.
//   Per edge: symbol byte from list8, one ds_read_b128 from the 9KB bf16 R
//   table (acc unpack identical to all prior passing rounds). Zero global
//   traffic in the inner loop. ll0 = lntab[x[n]][g].
//   LDS ~33KB -> 4 blocks/CU.
// ---------------------------------------------------------------------------
#define GACC(vv) { \
    acc[0] += bflo(vv.x); acc[1] += bfhi(vv.x); acc[2] += bflo(vv.y); acc[3] += bfhi(vv.y); \
    acc[4] += bflo(vv.z); acc[5] += bfhi(vv.z); acc[6] += bflo(vv.w); acc[7] += bfhi(vv.w); }
#define GEDGE(eb) { int ej_ = (eb) + sub16; \
    int xv_ = (ej_ < dd0) ? (int)list8[nb44 + ej_] : 32; \
    uint4 rv_ = *(const uint4*)(R16 + xv_ * RROW + (m16 << 3)); \
    GACC(rv_); }

__global__ __launch_bounds__(512) void place_aggr(
        const unsigned* __restrict__ segbuf,   // [NBK][P1B][SEGW]
        const int* __restrict__ x,
        const float* __restrict__ smB1ws,
        const float* __restrict__ smQgws,
        const unsigned short* __restrict__ Rws,
        const float* __restrict__ lntabws,
        const int* __restrict__ flag_ws,
        void* __restrict__ out) {
    __shared__ unsigned short R16[33 * RROW];   // 9.0 KB bf16 row table
    __shared__ float sQ[4341];                  // 17.4 KB swizzled Q table
    __shared__ float lnt[256];                  // 1 KB
    __shared__ unsigned char list8[BSZ * CAPk]; // 4.3 KB symbol lists
    __shared__ int cnt[BSZ];
    __shared__ int scl[P1B];
    int b = blockIdx.x, tid = threadIdx.x;
    const int isbf = flag_ws[0];
    const unsigned* strip = segbuf + (size_t)b * (P1B * SEGW);

    for (int t = tid; t < Cc * Cc * Gg; t += 512) {
        int g = t >> 8, i = (t >> 4) & 15, j = t & 15;
        sQ[g * 545 + i * 34 + j] = smQgws[t];
    }
    for (int t = tid; t < (33 * RROW) / 2; t += 512)
        ((unsigned*)R16)[t] = ((const unsigned*)Rws)[t];
    for (int t = tid; t < 256; t += 512) lnt[t] = lntabws[t];
    for (int i = tid; i < BSZ; i += 512) cnt[i] = 0;
    if (tid < P1B) scl[tid] = (int)strip[tid * SEGW];
    __syncthreads();

    {   // ---- place: coalesced strip scan -> LDS symbol lists ----
        for (int w = tid; w < P1B * SEGW; w += 512) {
            unsigned pk = strip[w];
            int seg = w / SEGW;
            int j   = w - seg * SEGW;
            if (j >= 1 && j <= scl[seg]) {
                int sl = (int)(pk >> 5);
                int pos = atomicAdd(&cnt[sl], 1);
                if (pos < CAPk) list8[sl * CAPk + pos] = (unsigned char)(pk & 31u);
            }
        }
    }
    __syncthreads();

    const int nbase = b * BSZ;
    int limt = Nn - nbase; if (limt > BSZ) limt = BSZ; if (limt < 0) limt = 0;

    // ---- ll0 output: lntab[x[n]][g] ----
    for (int t = tid; t < limt * 8; t += 512) {
        int n = t >> 3, g = t & 7;
        int xv = x[nbase + n];
        stout(out, (size_t)(nbase + n) * (2 * Gg) + g, lnt[xv * 8 + g], isbf);
    }

    // ---- aggregation + layer1 ----
    const int lane = tid & 63, wib = tid >> 6;     // 8 waves
    const int sub16 = lane >> 4, m16 = lane & 15;
    const int ii = lane >> 3, gW = lane & 7;
    const int i0 = 2 * ii, i1 = i0 + 1;
    const float* qp = sQ + gW * 545 + i0 * 34;

    for (int n = wib; n < limt; n += 8) {
        const int dv0 = cnt[n];                    // LDS broadcast
        const int dd0 = dv0 < CAPk ? dv0 : CAPk;
        const int nb44 = n * CAPk;
        int xvn = x[nbase + n];
        float b0c = smB1ws[i0 * (Mm * Gg) + xvn * Gg + gW];
        float b1c = smB1ws[i1 * (Mm * Gg) + xvn * Gg + gW];

        float acc[8];
#pragma unroll
        for (int j = 0; j < 8; ++j) acc[j] = 0.f;
        for (int e = 0; e < dd0; e += 4) GEDGE(e);

        // reduce the 4 edge sub-groups
#pragma unroll
        for (int j = 0; j < 8; ++j) {
            acc[j] += __shfl_xor(acc[j], 16, 64);
            acc[j] += __shfl_xor(acc[j], 32, 64);
        }
        // fused collect + dot (Q from swizzled LDS)
        float qa0 = 0.f, qa1 = 0.f;
#pragma unroll
        for (int j = 0; j < 8; ++j) {
            float t0 = __shfl(acc[j], 2 * gW, 64);       // aggr[gW][j]
            float t1 = __shfl(acc[j], 2 * gW + 1, 64);   // aggr[gW][8+j]
            qa0 += qp[j] * t0 + qp[8 + j] * t1;
            qa1 += qp[34 + j] * t0 + qp[42 + j] * t1;
        }
        float invd = 1.0f / fmaxf((float)dv0, 1.0f);
        qa0 *= invd; qa1 *= invd;
        float v0 = b0c * qa0, v1 = b1c * qa1;
        float nrm = v0 + v1;
        nrm += __shfl_xor(nrm, 8, 64);
        nrm += __shfl_xor(nrm, 16, 64);
        nrm += __shfl_xor(nrm, 32, 64);
        float invn = 1.0f / nrm;
        int ng = nbase + n;
        size_t pbase = (size_t)Nn * 2 * Gg + (size_t)ng * (Cc * Gg);
        stout(out, pbase + i0 * Gg + gW, v0 * invn, isbf);
        stout(out, pbase + i1 * Gg + gW, v1 * invn, isbf);
        if (ii == 0) stout(out, (size_t)ng * (2 * Gg) + Gg + gW, logf(nrm), isbf);
    }
}

// ---------------------------------------------------------------------------
extern "C" void kernel_launch(void* const* d_in, const int* in_sizes, int n_in,
                              void* d_out, int out_size, void* d_ws, size_t ws_size,
                              hipStream_t stream) {
    const int* x  = (const int*)d_in[0];
    const int* ei = (const int*)d_in[1];
    const void* B0 = d_in[2];
    const void* Pi = d_in[3];
    const void* B1 = d_in[4];
    const void* Q  = d_in[5];

    // ws: flag(128i) | smB1(4096f) | smQg(2048f) | lntab(256f) | R16(2304f as ushort)
    //   | segbuf (NBK*P1B*SEGW u32 = 12.8MB)
    float* ws = (float*)d_ws;
    int*   flag   = (int*)ws;                     // [0]=isbf
    float* smB1ws = ws + 128;                     // 4096 [i][m][g]
    float* smQgws = smB1ws + 4096;                // 2048 [g][i][l]
    float* lntabws = smQgws + 2048;               // 256 [m][g]
    unsigned short* Rws = (unsigned short*)(lntabws + 256);    // 33*136 bf16
    unsigned* segbuf = (unsigned*)(lntabws + 256 + 2304);      // [NBK][P1B][SEGW]

    bucket_tables<<<P1B + 1, 256, 0, stream>>>(
        ei, x, B0, Pi, B1, Q, segbuf, Rws, lntabws, smB1ws, smQgws, flag, d_out);

    place_aggr<<<NBK, 512, 0, stream>>>(
        segbuf, x, smB1ws, smQgws, Rws, lntabws, flag, d_out);
}

// Round 14
// 121.396 us; speedup vs baseline: 1.0901x; 1.0804x over previous
//
#include <hip/hip_runtime.h>
#include <hip/hip_bf16.h>
#include <math.h>

#define Nn 50000
#define Ee 800000
#define Cc 16
#define Mm 32
#define Gg 8

#define P1B 250           // pass-1 blocks (800 int4 quads = 3200 edges each)
#define NBK 1024          // src-range buckets
#define BSZ 49            // nodes per bucket (1024*49 = 50176 >= 50000)
#define SEGE 20           // edge capacity per (block,bucket) cell (mean 3.125, P(>20)~2e-11)
#define SEGW 21           // strip stride: [count][e0..e19]

// ---------------------------------------------------------------------------
// helpers
// ---------------------------------------------------------------------------
__device__ __forceinline__ float ldin(const void* p, int idx, int isbf) {
    if (isbf) return __bfloat162float(((const __hip_bfloat16*)p)[idx]);
    return ((const float*)p)[idx];
}
__device__ __forceinline__ void stout(void* p, size_t idx, float v, int isbf) {
    if (isbf) ((__hip_bfloat16*)p)[idx] = __float2bfloat16(v);
    else ((float*)p)[idx] = v;
}
__device__ __forceinline__ unsigned short f2bf(float f) {    // RNE f32 -> bf16 bits
    unsigned u = __float_as_uint(f);
    return (unsigned short)((u + 0x7FFFu + ((u >> 16) & 1u)) >> 16);
}
__device__ __forceinline__ float bflo(unsigned v) { return __uint_as_float(v << 16); }

__device__ __forceinline__ int detect_bf16(const void* B0, int tid, int* sflag) {
    if (tid < 64) {
        unsigned wv = ((const unsigned*)B0)[tid];
        unsigned ex = (wv >> 7) & 0xFFu;
        unsigned long long m = __ballot(ex >= 120u && ex <= 130u);
        if (tid == 0) *sflag = (__popcll(m) >= 48) ? 1 : 0;
    }
    __syncthreads();
    return *sflag;
}

// in-place softmax of one LDS column: entries base + k*stride, k in [0,cnt)
__device__ __forceinline__ void sm_col(float* a, int base, int stride, int cnt) {
    float mx = -1e30f;
    for (int k = 0; k < cnt; ++k) mx = fmaxf(mx, a[base + k * stride]);
    float s = 0.f;
    for (int k = 0; k < cnt; ++k) {
        float e = __expf(a[base + k * stride] - mx);
        a[base + k * stride] = e;
        s += e;
    }
    float inv = 1.0f / s;
    for (int k = 0; k < cnt; ++k) a[base + k * stride] *= inv;
}

// ---------------------------------------------------------------------------
// Kernel 1 (R14): blocks [0,P1B) = pass-1 scatter (512 thr, 8 waves/CU for
// x[dst] latency hiding); block P1B = table producer.
// R14 INSIGHT #2: aggr is a HISTOGRAM dot: aggr[n] = (1/d) sum_m hist[n][m]*R[m]
//   -> qa[i,g] = (1/d) sum_m hist[n][m]*QR[m][i][g], QR = Q.R precomputed here
//   (32x16x8 fp32). K2 needs no R table, no symbol lists, no per-edge unpack.
// R rows are bf16-rounded BEFORE the QR dot to preserve the established
// numeric profile. lntab gives ll0 = lntab[x[n]][g].
// ---------------------------------------------------------------------------
__global__ __launch_bounds__(512) void bucket_tables(
        const int* __restrict__ ei,
        const int* __restrict__ x,
        const void* __restrict__ B0,
        const void* __restrict__ Pi,
        const void* __restrict__ B1,
        const void* __restrict__ Q,
        unsigned* __restrict__ segbuf,     // [NBK][P1B][SEGW]
        float* __restrict__ lntabws,       // [32][8]
        float* __restrict__ smB1ws,        // [i][m][g] fp32
        float* __restrict__ QRws,          // [m][i][g] fp32 (4096)
        int* __restrict__ flag_ws) {
    int b = blockIdx.x, tid = threadIdx.x;
    __shared__ unsigned shb[NBK + NBK * SEGE];     // 86 KB unioned buffer
    __shared__ int sflag;

    if (b < P1B) {   // ---- pass 1: bucket scatter with symbol resolution ----
        int* scnt = (int*)shb;            // 1024 counters
        unsigned* sstage = shb + NBK;     // 1024*20 staged packed words
        for (int i = tid; i < NBK; i += 512) scnt[i] = 0;
        __syncthreads();
        const int4* ei4 = (const int4*)ei;
        const int qbase = b * 800;                 // 800 quads = 3200 edges
        for (int q = tid; q < 800; q += 512) {
            int4 sv = ei4[qbase + q];
            int4 dv = ei4[200000 + qbase + q];     // Ee/4 = 200000
            int ds_[4] = { dv.x, dv.y, dv.z, dv.w };
            int xs_[4];
#pragma unroll
            for (int k = 0; k < 4; ++k) xs_[k] = x[ds_[k]];   // batched L2 loads
#pragma unroll
            for (int k = 0; k < 4; ++k) {
                int s = (k == 0) ? sv.x : (k == 1) ? sv.y : (k == 2) ? sv.z : sv.w;
                int bk = s / BSZ;                  // magic-mul division
                int pos = atomicAdd(&scnt[bk], 1); // LDS atomic
                if (pos < SEGE)
                    sstage[bk * SEGE + pos] =
                        ((unsigned)(s - bk * BSZ) << 5) | (unsigned)xs_[k];
            }
        }
        __syncthreads();
        // dense flush: full 21-word cell per bucket, word 0 = count
        for (int idx = tid; idx < NBK * SEGW; idx += 512) {
            int bk = idx / SEGW;
            int j  = idx - bk * SEGW;
            int c  = scnt[bk]; c = c < SEGE ? c : SEGE;
            unsigned v = (j == 0) ? (unsigned)c : sstage[bk * SEGE + (j - 1)];
            segbuf[((size_t)bk * P1B + b) * SEGW + j] = v;
        }
        return;
    }

    // ---- table producer block (b == P1B), sequential phases ----
    float* sh = (float*)shb;
    const int isbf = detect_bf16(B0, tid, &sflag);
    if (tid == 0) flag_ws[0] = isbf;
    // Phase 1: B1 softmax -> smB1ws
    for (int i = tid; i < Cc * Mm * Gg; i += 512) sh[i] = ldin(B1, i, isbf);
    __syncthreads();
    if (tid < 128) sm_col(sh, (tid >> 3) * (Mm * Gg) + (tid & 7), Gg, Mm);
    __syncthreads();
    for (int i = tid; i < Cc * Mm * Gg; i += 512) smB1ws[i] = sh[i];
    __syncthreads();
    // Phase 2: Q softmax -> sQg LDS ([g][i][l])
    for (int i = tid; i < Cc * Cc * Gg; i += 512) sh[i] = ldin(Q, i, isbf);
    __syncthreads();
    if (tid < 128) sm_col(sh, (tid >> 3) * Gg + (tid & 7), Cc * Gg, Cc);
    __syncthreads();
    float* sQg = sh + 4608;                 // 2048
    for (int t = tid; t < Cc * Cc * Gg; t += 512) {
        int i = t >> 7, rem = t & 127, l = rem >> 3, g = rem & 7;
        sQg[g * 256 + i * 16 + l] = sh[t];
    }
    __syncthreads();
    // Phase 3: B0 + Pi softmax -> lntab, sInv
    float* sB0 = sh;                        // 4096, [c][m][g]
    float* sPi = sh + 4096;                 // 128,  [c][g]
    float* sInv = sh + 4224;                // 256,  [m][g]
    for (int i = tid; i < Cc * Mm * Gg; i += 512) sB0[i] = ldin(B0, i, isbf);
    if (tid < Cc * Gg) sPi[tid] = ldin(Pi, tid, isbf);
    __syncthreads();
    if (tid < 128) {
        sm_col(sB0, (tid >> 3) * (Mm * Gg) + (tid & 7), Gg, Mm);
    } else if (tid < 128 + Gg) {
        sm_col(sPi, tid - 128, Gg, Cc);
    }
    __syncthreads();
    if (tid < Mm * Gg) {                    // norms per (symbol m, g)
        int mm = tid >> 3, g = tid & 7;
        float s = 0.f;
#pragma unroll
        for (int c = 0; c < Cc; ++c) s += sPi[c * Gg + g] * sB0[c * (Mm * Gg) + mm * Gg + g];
        lntabws[tid] = logf(s);
        sInv[tid] = 1.0f / s;
    }
    __syncthreads();
    // Phase 4: Rf (bf16-rounded posterior rows) -> QR = Q.R
    float* sRf = sh + 6656;                 // 4096 [m][l][g]
    for (int t = tid; t < 4096; t += 512) {
        int m = t >> 7, rem = t & 127, l = rem >> 3, g = rem & 7;
        float pv = sPi[l * 8 + g] * sB0[l * (Mm * Gg) + m * 8 + g] * sInv[m * 8 + g];
        sRf[t] = bflo((unsigned)f2bf(pv));
    }
    __syncthreads();
    for (int t = tid; t < 4096; t += 512) {
        int m = t >> 7, rem = t & 127, i = rem >> 3, g = rem & 7;
        float s = 0.f;
#pragma unroll
        for (int l = 0; l < 16; ++l) s += sQg[g * 256 + i * 16 + l] * sRf[m * 128 + l * 8 + g];
        QRws[t] = s;
    }
}

// ---------------------------------------------------------------------------
// Kernel 2 (R14): place (hist LDS atomics) + histogram-dot layer1.
//   Per edge: ONE atomicAdd(&hist[pk],1) (packed word IS the hist index).
//   Per node: 8x int4 hist reads + 64 FMA against the QR LDS table + 3
//   shuffles. No R table, no symbol lists, no per-edge unpack, no CAP drops.
//   LDS ~27KB -> grid 1024 = 4 blocks/CU = 32 waves/CU.
// ---------------------------------------------------------------------------
__global__ __launch_bounds__(512) void place_aggr(
        const unsigned* __restrict__ segbuf,   // [NBK][P1B][SEGW]
        const int* __restrict__ x,
        const float* __restrict__ smB1ws,
        const float* __restrict__ QRws,
        const float* __restrict__ lntabws,
        const int* __restrict__ flag_ws,
        void* __restrict__ out) {
    __shared__ float sQR[32 * 144];         // 18 KB, [m][i*9+g] (2-way banks)
    __shared__ float lnt[256];              // 1 KB
    __shared__ int hist[BSZ * 32];          // 6.1 KB, [node][symbol]
    __shared__ int scl[256];                // 250 segment counts
    int b = blockIdx.x, tid = threadIdx.x;
    const int isbf = flag_ws[0];
    const unsigned* strip = segbuf + (size_t)b * (P1B * SEGW);

    for (int t = tid; t < 4096; t += 512) {
        int m = t >> 7, rem = t & 127, i = rem >> 3, g = rem & 7;
        sQR[m * 144 + i * 9 + g] = QRws[t];
    }
    for (int t = tid; t < 256; t += 512) lnt[t] = lntabws[t];
    for (int t = tid; t < BSZ * 32; t += 512) hist[t] = 0;
    if (tid < P1B) scl[tid] = (int)strip[tid * SEGW];
    __syncthreads();

    {   // ---- place: coalesced strip scan -> hist ----
        for (int w = tid; w < P1B * SEGW; w += 512) {
            unsigned pk = strip[w];
            int seg = w / SEGW;
            int j   = w - seg * SEGW;
            if (j >= 1 && j <= scl[seg])
                atomicAdd(&hist[pk], 1);           // pk = sl*32+xv < 1568
        }
    }
    __syncthreads();

    const int nbase = b * BSZ;
    int limt = Nn - nbase; if (limt > BSZ) limt = BSZ; if (limt < 0) limt = 0;

    // ---- ll0 output: lntab[x[n]][g] ----
    for (int t = tid; t < limt * 8; t += 512) {
        int n = t >> 3, g = t & 7;
        stout(out, (size_t)(nbase + n) * (2 * Gg) + g, lnt[x[nbase + n] * 8 + g], isbf);
    }

    // ---- histogram-dot layer1 ----
    const int lane = tid & 63, wib = tid >> 6;     // 8 waves
    const int ii = lane >> 3, gW = lane & 7;
    const int i0 = 2 * ii, i1 = i0 + 1;
    const float* q0 = sQR + i0 * 9 + gW;           // + m*144
    const float* q1 = q0 + 9;

    for (int n = wib; n < limt; n += 8) {
        const int* hp = hist + n * 32;
        int xvn = x[nbase + n];
        float b0c = smB1ws[i0 * (Mm * Gg) + xvn * Gg + gW];
        float b1c = smB1ws[i1 * (Mm * Gg) + xvn * Gg + gW];
        float qa0 = 0.f, qa1 = 0.f;
        int d = 0;
#pragma unroll
        for (int mm = 0; mm < 8; ++mm) {
            int4 hv = ((const int4*)hp)[mm];       // broadcast b128
            int m4 = mm * 4;
            d += hv.x + hv.y + hv.z + hv.w;
            qa0 += (float)hv.x * q0[(m4 + 0) * 144] + (float)hv.y * q0[(m4 + 1) * 144]
                 + (float)hv.z * q0[(m4 + 2) * 144] + (float)hv.w * q0[(m4 + 3) * 144];
            qa1 += (float)hv.x * q1[(m4 + 0) * 144] + (float)hv.y * q1[(m4 + 1) * 144]
                 + (float)hv.z * q1[(m4 + 2) * 144] + (float)hv.w * q1[(m4 + 3) * 144];
        }
        float invd = 1.0f / fmaxf((float)d, 1.0f);
        qa0 *= invd; qa1 *= invd;
        float v0 = b0c * qa0, v1 = b1c * qa1;
        float nrm = v0 + v1;
        nrm += __shfl_xor(nrm, 8, 64);
        nrm += __shfl_xor(nrm, 16, 64);
        nrm += __shfl_xor(nrm, 32, 64);
        float invn = 1.0f / nrm;
        int ng = nbase + n;
        size_t pbase = (size_t)Nn * 2 * Gg + (size_t)ng * (Cc * Gg);
        stout(out, pbase + i0 * Gg + gW, v0 * invn, isbf);
        stout(out, pbase + i1 * Gg + gW, v1 * invn, isbf);
        if (ii == 0) stout(out, (size_t)ng * (2 * Gg) + Gg + gW, logf(nrm), isbf);
    }
}

// ---------------------------------------------------------------------------
extern "C" void kernel_launch(void* const* d_in, const int* in_sizes, int n_in,
                              void* d_out, int out_size, void* d_ws, size_t ws_size,
                              hipStream_t stream) {
    const int* x  = (const int*)d_in[0];
    const int* ei = (const int*)d_in[1];
    const void* B0 = d_in[2];
    const void* Pi = d_in[3];
    const void* B1 = d_in[4];
    const void* Q  = d_in[5];

    // ws: flag(128i) | smB1(4096f) | lntab(256f) | QR(4096f) | segbuf (~20.5MB)
    float* ws = (float*)d_ws;
    int*   flag    = (int*)ws;                    // [0]=isbf
    float* smB1ws  = ws + 128;                    // 4096 [i][m][g]
    float* lntabws = smB1ws + 4096;               // 256 [m][g]
    float* QRws    = lntabws + 256;               // 4096 [m][i][g]
    unsigned* segbuf = (unsigned*)(QRws + 4096);  // [NBK][P1B][SEGW]

    bucket_tables<<<P1B + 1, 512, 0, stream>>>(
        ei, x, B0, Pi, B1, Q, segbuf, lntabws, smB1ws, QRws, flag);

    place_aggr<<<NBK, 512, 0, stream>>>(
        segbuf, x, smB1ws, QRws, lntabws, flag, d_out);
}

// Round 15
// 112.435 us; speedup vs baseline: 1.1770x; 1.0797x over previous
//
#include <hip/hip_runtime.h>
#include <hip/hip_bf16.h>
#include <math.h>

#define Nn 50000
#define Ee 800000
#define Cc 16
#define Mm 32
#define Gg 8

#define P1B 250           // pass-1 scatter blocks (800 int4 quads = 3200 edges each)
#define NBK 1024          // src-range buckets
#define BSZ 49            // nodes per bucket (1024*49 = 50176 >= 50000)
#define SEGE 20           // edge capacity per cell (mean 3.125, P(>20)~2e-11/cell)
#define SEGW 11           // strip stride in u32: [count][10 words = 20 u16 edges]

// ---------------------------------------------------------------------------
// helpers
// ---------------------------------------------------------------------------
__device__ __forceinline__ float ldin(const void* p, int idx, int isbf) {
    if (isbf) return __bfloat162float(((const __hip_bfloat16*)p)[idx]);
    return ((const float*)p)[idx];
}
__device__ __forceinline__ void stout(void* p, size_t idx, float v, int isbf) {
    if (isbf) ((__hip_bfloat16*)p)[idx] = __float2bfloat16(v);
    else ((float*)p)[idx] = v;
}
__device__ __forceinline__ unsigned short f2bf(float f) {    // RNE f32 -> bf16 bits
    unsigned u = __float_as_uint(f);
    return (unsigned short)((u + 0x7FFFu + ((u >> 16) & 1u)) >> 16);
}
__device__ __forceinline__ float bflo(unsigned v) { return __uint_as_float(v << 16); }

__device__ __forceinline__ int detect_bf16(const void* B0, int tid, int* sflag) {
    if (tid < 64) {
        unsigned wv = ((const unsigned*)B0)[tid];
        unsigned ex = (wv >> 7) & 0xFFu;
        unsigned long long m = __ballot(ex >= 120u && ex <= 130u);
        if (tid == 0) *sflag = (__popcll(m) >= 48) ? 1 : 0;
    }
    __syncthreads();
    return *sflag;
}

// in-place softmax of one LDS column: entries base + k*stride, k in [0,cnt)
__device__ __forceinline__ void sm_col(float* a, int base, int stride, int cnt) {
    float mx = -1e30f;
    for (int k = 0; k < cnt; ++k) mx = fmaxf(mx, a[base + k * stride]);
    float s = 0.f;
    for (int k = 0; k < cnt; ++k) {
        float e = __expf(a[base + k * stride] - mx);
        a[base + k * stride] = e;
        s += e;
    }
    float inv = 1.0f / s;
    for (int k = 0; k < cnt; ++k) a[base + k * stride] *= inv;
}

// ---------------------------------------------------------------------------
// Kernel 1 (R15): blocks [0,P1B) = pass-1 scatter at 1024 threads (16 waves/CU
// for x[dst] latency cover; was 512 = 8); block P1B = table producer.
// u16 edge packing: edge = 11 bits -> two per u32; cell = [count][<=10 words].
// SPARSE flush: thread-per-cell (1024 threads = NBK), writes only
// count + ceil(c/2) words (~5MB actual vs R14's 21.5MB dense).
// ---------------------------------------------------------------------------
__global__ __launch_bounds__(1024) void bucket_tables(
        const int* __restrict__ ei,
        const int* __restrict__ x,
        const void* __restrict__ B0,
        const void* __restrict__ Pi,
        const void* __restrict__ B1,
        const void* __restrict__ Q,
        unsigned* __restrict__ segbuf,     // [NBK][P1B][SEGW]
        float* __restrict__ lntabws,       // [32][8]
        float* __restrict__ smB1ws,        // [i][m][g] fp32
        float* __restrict__ QRws,          // [m][i][g] fp32 (4096)
        int* __restrict__ flag_ws) {
    int b = blockIdx.x, tid = threadIdx.x;
    __shared__ unsigned shb[11264];                // 45 KB unioned buffer
    __shared__ int sflag;

    if (b < P1B) {   // ---- pass 1: bucket scatter with symbol resolution ----
        int* scnt = (int*)shb;                              // 1024 counters
        unsigned short* sstage = (unsigned short*)(shb + 1024);  // 1024*20 u16
        scnt[tid] = 0;
        __syncthreads();
        const int4* ei4 = (const int4*)ei;
        const int qbase = b * 800;                 // 800 quads = 3200 edges
        if (tid < 800) {
            int q = qbase + tid;
            int4 sv = ei4[q];
            int4 dv = ei4[200000 + q];             // Ee/4 = 200000
            int ds_[4] = { dv.x, dv.y, dv.z, dv.w };
            int xs_[4];
#pragma unroll
            for (int k = 0; k < 4; ++k) xs_[k] = x[ds_[k]];   // batched L2 loads
#pragma unroll
            for (int k = 0; k < 4; ++k) {
                int s = (k == 0) ? sv.x : (k == 1) ? sv.y : (k == 2) ? sv.z : sv.w;
                int bk = s / BSZ;                  // magic-mul division
                int pos = atomicAdd(&scnt[bk], 1); // LDS atomic
                if (pos < SEGE)
                    sstage[bk * SEGE + pos] =
                        (unsigned short)(((s - bk * BSZ) << 5) | xs_[k]);
            }
        }
        __syncthreads();
        {   // sparse flush: thread tid owns bucket tid (exactly NBK threads)
            int c = scnt[tid]; c = c < SEGE ? c : SEGE;
            unsigned* cell = segbuf + ((size_t)tid * P1B + b) * SEGW;
            cell[0] = (unsigned)c;
            const unsigned short* st = sstage + tid * SEGE;
            int nw = (c + 1) >> 1;
            for (int w = 0; w < nw; ++w)
                cell[1 + w] = (unsigned)st[2 * w] | ((unsigned)st[2 * w + 1] << 16);
        }
        return;
    }

    // ---- table producer block (b == P1B), sequential phases ----
    float* sh = (float*)shb;
    const int isbf = detect_bf16(B0, tid, &sflag);
    if (tid == 0) flag_ws[0] = isbf;
    // Phase 1: B1 softmax -> smB1ws
    for (int i = tid; i < Cc * Mm * Gg; i += 1024) sh[i] = ldin(B1, i, isbf);
    __syncthreads();
    if (tid < 128) sm_col(sh, (tid >> 3) * (Mm * Gg) + (tid & 7), Gg, Mm);
    __syncthreads();
    for (int i = tid; i < Cc * Mm * Gg; i += 1024) smB1ws[i] = sh[i];
    __syncthreads();
    // Phase 2: Q softmax -> sQg LDS ([g][i][l])
    for (int i = tid; i < Cc * Cc * Gg; i += 1024) sh[i] = ldin(Q, i, isbf);
    __syncthreads();
    if (tid < 128) sm_col(sh, (tid >> 3) * Gg + (tid & 7), Cc * Gg, Cc);
    __syncthreads();
    float* sQg = sh + 4608;                 // 2048
    for (int t = tid; t < Cc * Cc * Gg; t += 1024) {
        int i = t >> 7, rem = t & 127, l = rem >> 3, g = rem & 7;
        sQg[g * 256 + i * 16 + l] = sh[t];
    }
    __syncthreads();
    // Phase 3: B0 + Pi softmax -> lntab, sInv
    float* sB0 = sh;                        // 4096, [c][m][g]
    float* sPi = sh + 4096;                 // 128,  [c][g]
    float* sInv = sh + 4224;                // 256,  [m][g]
    for (int i = tid; i < Cc * Mm * Gg; i += 1024) sB0[i] = ldin(B0, i, isbf);
    if (tid < Cc * Gg) sPi[tid] = ldin(Pi, tid, isbf);
    __syncthreads();
    if (tid < 128) {
        sm_col(sB0, (tid >> 3) * (Mm * Gg) + (tid & 7), Gg, Mm);
    } else if (tid < 128 + Gg) {
        sm_col(sPi, tid - 128, Gg, Cc);
    }
    __syncthreads();
    if (tid < Mm * Gg) {                    // norms per (symbol m, g)
        int mm = tid >> 3, g = tid & 7;
        float s = 0.f;
#pragma unroll
        for (int c = 0; c < Cc; ++c) s += sPi[c * Gg + g] * sB0[c * (Mm * Gg) + mm * Gg + g];
        lntabws[tid] = logf(s);
        sInv[tid] = 1.0f / s;
    }
    __syncthreads();
    // Phase 4: Rf (bf16-rounded posterior rows) -> QR = Q.R
    float* sRf = sh + 6656;                 // 4096 [m][l][g]
    for (int t = tid; t < 4096; t += 1024) {
        int m = t >> 7, rem = t & 127, l = rem >> 3, g = rem & 7;
        float pv = sPi[l * 8 + g] * sB0[l * (Mm * Gg) + m * 8 + g] * sInv[m * 8 + g];
        sRf[t] = bflo((unsigned)f2bf(pv));
    }
    __syncthreads();
    for (int t = tid; t < 4096; t += 1024) {
        int m = t >> 7, rem = t & 127, i = rem >> 3, g = rem & 7;
        float s = 0.f;
#pragma unroll
        for (int l = 0; l < 16; ++l) s += sQg[g * 256 + i * 16 + l] * sRf[m * 128 + l * 8 + g];
        QRws[t] = s;
    }
}

// ---------------------------------------------------------------------------
// Kernel 2 (R15): place (sparse per-segment strip read, 2 threads/segment,
// only count-validated words touched -> ~4MB total read vs R14's 21.5MB)
// + histogram-dot layer1 (unchanged from R14).
// LDS ~27KB -> grid 1024 = 4 blocks/CU = 32 waves/CU.
// ---------------------------------------------------------------------------
__global__ __launch_bounds__(512) void place_aggr(
        const unsigned* __restrict__ segbuf,   // [NBK][P1B][SEGW]
        const int* __restrict__ x,
        const float* __restrict__ smB1ws,
        const float* __restrict__ QRws,
        const float* __restrict__ lntabws,
        const int* __restrict__ flag_ws,
        void* __restrict__ out) {
    __shared__ float sQR[32 * 144];         // 18 KB, [m][i*9+g] (2-way banks)
    __shared__ float lnt[256];              // 1 KB
    __shared__ int hist[BSZ * 32];          // 6.1 KB, [node][symbol]
    __shared__ int scl[256];                // 250 segment counts
    int b = blockIdx.x, tid = threadIdx.x;
    const int isbf = flag_ws[0];
    const unsigned* strip = segbuf + (size_t)b * (P1B * SEGW);

    for (int t = tid; t < 4096; t += 512) {
        int m = t >> 7, rem = t & 127, i = rem >> 3, g = rem & 7;
        sQR[m * 144 + i * 9 + g] = QRws[t];
    }
    for (int t = tid; t < 256; t += 512) lnt[t] = lntabws[t];
    for (int t = tid; t < BSZ * 32; t += 512) hist[t] = 0;
    if (tid < P1B) scl[tid] = (int)strip[tid * SEGW];
    __syncthreads();

    {   // ---- place: 2 threads per segment, valid words only ----
        if (tid < 2 * P1B) {
            int seg = tid >> 1, par = tid & 1;
            int c = scl[seg];
            int nw = (c + 1) >> 1;
            const unsigned* sp = strip + seg * SEGW + 1;
            for (int w = par; w < nw; w += 2) {
                unsigned pk = sp[w];
                atomicAdd(&hist[pk & 0x7ffu], 1);
                int e2 = 2 * w + 1;
                if (e2 < c) atomicAdd(&hist[(pk >> 16) & 0x7ffu], 1);
            }
        }
    }
    __syncthreads();

    const int nbase = b * BSZ;
    int limt = Nn - nbase; if (limt > BSZ) limt = BSZ; if (limt < 0) limt = 0;

    // ---- ll0 output: lntab[x[n]][g] ----
    for (int t = tid; t < limt * 8; t += 512) {
        int n = t >> 3, g = t & 7;
        stout(out, (size_t)(nbase + n) * (2 * Gg) + g, lnt[x[nbase + n] * 8 + g], isbf);
    }

    // ---- histogram-dot layer1 ----
    const int lane = tid & 63, wib = tid >> 6;     // 8 waves
    const int ii = lane >> 3, gW = lane & 7;
    const int i0 = 2 * ii, i1 = i0 + 1;
    const float* q0 = sQR + i0 * 9 + gW;           // + m*144
    const float* q1 = q0 + 9;

    for (int n = wib; n < limt; n += 8) {
        const int* hp = hist + n * 32;
        int xvn = x[nbase + n];
        float b0c = smB1ws[i0 * (Mm * Gg) + xvn * Gg + gW];
        float b1c = smB1ws[i1 * (Mm * Gg) + xvn * Gg + gW];
        float qa0 = 0.f, qa1 = 0.f;
        int d = 0;
#pragma unroll
        for (int mm = 0; mm < 8; ++mm) {
            int4 hv = ((const int4*)hp)[mm];       // broadcast b128
            int m4 = mm * 4;
            d += hv.x + hv.y + hv.z + hv.w;
            qa0 += (float)hv.x * q0[(m4 + 0) * 144] + (float)hv.y * q0[(m4 + 1) * 144]
                 + (float)hv.z * q0[(m4 + 2) * 144] + (float)hv.w * q0[(m4 + 3) * 144];
            qa1 += (float)hv.x * q1[(m4 + 0) * 144] + (float)hv.y * q1[(m4 + 1) * 144]
                 + (float)hv.z * q1[(m4 + 2) * 144] + (float)hv.w * q1[(m4 + 3) * 144];
        }
        float invd = 1.0f / fmaxf((float)d, 1.0f);
        qa0 *= invd; qa1 *= invd;
        float v0 = b0c * qa0, v1 = b1c * qa1;
        float nrm = v0 + v1;
        nrm += __shfl_xor(nrm, 8, 64);
        nrm += __shfl_xor(nrm, 16, 64);
        nrm += __shfl_xor(nrm, 32, 64);
        float invn = 1.0f / nrm;
        int ng = nbase + n;
        size_t pbase = (size_t)Nn * 2 * Gg + (size_t)ng * (Cc * Gg);
        stout(out, pbase + i0 * Gg + gW, v0 * invn, isbf);
        stout(out, pbase + i1 * Gg + gW, v1 * invn, isbf);
        if (ii == 0) stout(out, (size_t)ng * (2 * Gg) + Gg + gW, logf(nrm), isbf);
    }
}

// ---------------------------------------------------------------------------
extern "C" void kernel_launch(void* const* d_in, const int* in_sizes, int n_in,
                              void* d_out, int out_size, void* d_ws, size_t ws_size,
                              hipStream_t stream) {
    const int* x  = (const int*)d_in[0];
    const int* ei = (const int*)d_in[1];
    const void* B0 = d_in[2];
    const void* Pi = d_in[3];
    const void* B1 = d_in[4];
    const void* Q  = d_in[5];

    // ws: flag(128i) | smB1(4096f) | lntab(256f) | QR(4096f) | segbuf (11.3MB)
    float* ws = (float*)d_ws;
    int*   flag    = (int*)ws;                    // [0]=isbf
    float* smB1ws  = ws + 128;                    // 4096 [i][m][g]
    float* lntabws = smB1ws + 4096;               // 256 [m][g]
    float* QRws    = lntabws + 256;               // 4096 [m][i][g]
    unsigned* segbuf = (unsigned*)(QRws + 4096);  // [NBK][P1B][SEGW]

    bucket_tables<<<P1B + 1, 1024, 0, stream>>>(
        ei, x, B0, Pi, B1, Q, segbuf, lntabws, smB1ws, QRws, flag);

    place_aggr<<<NBK, 512, 0, stream>>>(
        segbuf, x, smB1ws, QRws, lntabws, flag, d_out);
}